// Round 2
// baseline (97.748 us; speedup 1.0000x reference)
//
#include <hip/hip_runtime.h>
#include <math.h>

#define B_ROWS 4096
#define NVIEW 2
#define DIM 128
#define LBL 100
#define VB 8192
#define NCHUNK 16
#define CHUNK 512

typedef __attribute__((ext_vector_type(8))) short bf16x8;
typedef __attribute__((ext_vector_type(4))) float f32x4;

__device__ __forceinline__ unsigned short f2bf(float x) {
  union { float f; unsigned u; } a; a.f = x;
  unsigned r = a.u + 0x7fffu + ((a.u >> 16) & 1u);  // RNE
  return (unsigned short)(r >> 16);
}

__global__ void zero_kernel(float* accum) {
  if (threadIdx.x < 2) accum[threadIdx.x] = 0.0f;
}

// One wave per contrast-feature row j (j<B: view0, else view1).
// Produces: cfA = bf16(f/T) rows [0,B); cfB = bf16(f) rows [0,VB);
//           Lb = 128-bit label masks; rsv = label row sums.
__global__ void pack_kernel(const float* __restrict__ feat,
                            const float* __restrict__ labels,
                            unsigned short* __restrict__ cfA,
                            unsigned short* __restrict__ cfB,
                            uint4* __restrict__ Lb,
                            int* __restrict__ rsv) {
  const float invT = 1.0f / 0.07f;
  int w = (int)((blockIdx.x * blockDim.x + threadIdx.x) >> 6);
  int lane = threadIdx.x & 63;
  if (w >= VB) return;
  int b = w & (B_ROWS - 1);
  int v = w >> 12;
  const float2* src = (const float2*)(feat + ((size_t)b * NVIEW + v) * DIM);
  float2 f = src[lane];
  ((unsigned*)(cfB + (size_t)w * DIM))[lane] =
      (unsigned)f2bf(f.x) | ((unsigned)f2bf(f.y) << 16);
  if (v == 0) {  // wave-uniform
    ((unsigned*)(cfA + (size_t)w * DIM))[lane] =
        (unsigned)f2bf(f.x * invT) | ((unsigned)f2bf(f.y * invT) << 16);
    float x0 = labels[(size_t)w * LBL + lane];
    float x1 = (lane < LBL - 64) ? labels[(size_t)w * LBL + 64 + lane] : 0.0f;
    unsigned long long b0 = __ballot(x0 != 0.0f);
    unsigned long long b1 = __ballot(x1 != 0.0f);
    if (lane == 0) {
      Lb[w] = make_uint4((unsigned)b0, (unsigned)(b0 >> 32),
                         (unsigned)b1, (unsigned)(b1 >> 32));
      rsv[w] = __popcll(b0) + __popcll(b1);
    }
  }
}

// Main fused kernel: 128-row x 512-col block; MFMA dots + online softmax with
// underflow fast path. LDS tiles stored as 16B chunks: chunk(r,kc)=kc*128+(r^kc)
// (XOR swizzle -> conflict-free frag reads AND staged writes).
__launch_bounds__(256, 2)
__global__ void main_kernel(const unsigned short* __restrict__ cfA,
                            const unsigned short* __restrict__ cfB,
                            const uint4* __restrict__ Lb,
                            const int* __restrict__ rsv,
                            float4* __restrict__ part) {
  __shared__ uint4 As[2048];  // 32 KB: 128 rows x K=128 bf16
  __shared__ uint4 Bs[2048];  // 32 KB
  const int tid = threadIdx.x;
  const int lane = tid & 63;
  const int wave = tid >> 6;
  const int l15 = lane & 15;
  const int quad = lane >> 4;
  const int wi = (wave & 1) * 64;   // wave row offset in 128
  const int wj = (wave >> 1) * 64;  // wave col offset in 128
  const int rowBase = blockIdx.x * 128;
  const int chunkBase = blockIdx.y * CHUNK;
  const bool maskRegion = (chunkBase < B_ROWS);

  {  // stage A once (rows fixed for whole block)
    const uint4* srcA = (const uint4*)(cfA + (size_t)rowBase * DIM);
    #pragma unroll
    for (int it = 0; it < 8; ++it) {
      int flat = it * 256 + tid;
      int r = flat >> 4, kc = flat & 15;
      As[kc * 128 + (r ^ kc)] = srcA[flat];
    }
  }

  // online-softmax state: 16 rows per lane (fixed quad): row=wi+ti*16+quad*4+r
  float m_s[16], p_s[16], n_s[16];
  #pragma unroll
  for (int i = 0; i < 16; ++i) { m_s[i] = -INFINITY; p_s[i] = 0.f; n_s[i] = 0.f; }

  const bf16x8* Asv = (const bf16x8*)As;
  const bf16x8* Bsv = (const bf16x8*)Bs;

  for (int jt = 0; jt < 4; ++jt) {
    const int colBase = chunkBase + jt * 128;
    __syncthreads();
    {
      const uint4* srcB = (const uint4*)(cfB + (size_t)colBase * DIM);
      #pragma unroll
      for (int it = 0; it < 8; ++it) {
        int flat = it * 256 + tid;
        int r = flat >> 4, kc = flat & 15;
        Bs[kc * 128 + (r ^ kc)] = srcB[flat];
      }
    }
    __syncthreads();

    f32x4 acc[4][4];
    #pragma unroll
    for (int ti = 0; ti < 4; ++ti)
      #pragma unroll
      for (int tj = 0; tj < 4; ++tj)
        acc[ti][tj] = (f32x4){0.f, 0.f, 0.f, 0.f};

    #pragma unroll
    for (int ks = 0; ks < 4; ++ks) {
      const int kc = ks * 4 + quad;
      const int abase = kc * 128 + wi + (l15 ^ kc);
      const int bbase = kc * 128 + wj + (l15 ^ kc);
      bf16x8 af[4], bfr[4];
      #pragma unroll
      for (int t = 0; t < 4; ++t) {
        af[t] = Asv[abase + t * 16];
        bfr[t] = Bsv[bbase + t * 16];
      }
      #pragma unroll
      for (int ti = 0; ti < 4; ++ti)
        #pragma unroll
        for (int tj = 0; tj < 4; ++tj)
          acc[ti][tj] = __builtin_amdgcn_mfma_f32_16x16x32_bf16(
              af[ti], bfr[tj], acc[ti][tj], 0, 0, 0);
    }

    // epilogue: C[row][col], row=wi+ti*16+quad*4+r, col=wj+tj*16+l15 (+bases)
    if (!maskRegion) {
      #pragma unroll
      for (int ti = 0; ti < 4; ++ti)
        #pragma unroll
        for (int r = 0; r < 4; ++r) {
          float tm = fmaxf(fmaxf(acc[ti][0][r], acc[ti][1][r]),
                           fmaxf(acc[ti][2][r], acc[ti][3][r]));
          int si = ti * 4 + r;
          m_s[si] = fmaxf(m_s[si], tm);
        }
    } else {
      #pragma unroll
      for (int ti = 0; ti < 4; ++ti)
        #pragma unroll
        for (int r = 0; r < 4; ++r) {
          int si = ti * 4 + r;
          float l0 = acc[ti][0][r], l1 = acc[ti][1][r];
          float l2 = acc[ti][2][r], l3 = acc[ti][3][r];
          float tm = fmaxf(fmaxf(l0, l1), fmaxf(l2, l3));
          float m = m_s[si];
          if (tm > m - 90.0f) {  // slow path: something survives exp
            int grow = rowBase + wi + ti * 16 + quad * 4 + r;
            uint4 la = Lb[grow];
            int ra = rsv[grow];
            float newm = fmaxf(m, tm);
            float sc = __expf(m - newm);  // m=-inf -> 0
            float p = p_s[si] * sc, n = n_s[si] * sc;
            float lv[4] = {l0, l1, l2, l3};
            #pragma unroll
            for (int tj = 0; tj < 4; ++tj) {
              float e = __expf(lv[tj] - newm);
              int gcol = colBase + wj + tj * 16 + l15;
              uint4 lb = Lb[gcol];
              int rb = rsv[gcol];
              int inter = __popc(la.x & lb.x) + __popc(la.y & lb.y) +
                          __popc(la.z & lb.z) + __popc(la.w & lb.w);
              if (3 * inter > ra + rb) p += e; else n += e;  // sim>=0.5 exact
            }
            m_s[si] = newm; p_s[si] = p; n_s[si] = n;
          }
        }
    }
  }

  // reduce across the 16 lanes (same quad) that share each row
  #pragma unroll
  for (int si = 0; si < 16; ++si) {
    float m = m_s[si], p = p_s[si], n = n_s[si];
    #pragma unroll
    for (int off = 8; off >= 1; off >>= 1) {
      float om = __shfl_xor(m, off);
      float op = __shfl_xor(p, off);
      float on = __shfl_xor(n, off);
      float nm = fmaxf(m, om);
      float s0 = __expf(m - nm), s1 = __expf(om - nm);
      p = p * s0 + op * s1;
      n = n * s0 + on * s1;
      m = nm;
    }
    m_s[si] = m; p_s[si] = p; n_s[si] = n;
  }

  // merge the two waves sharing each row (wj=0 and wj=64) via LDS, then store
  __syncthreads();
  float* mbuf = (float*)As;
  if (wj == 64 && l15 == 0) {
    #pragma unroll
    for (int ti = 0; ti < 4; ++ti)
      #pragma unroll
      for (int r = 0; r < 4; ++r) {
        int row = wi + ti * 16 + quad * 4 + r;
        int si = ti * 4 + r;
        mbuf[row * 3 + 0] = m_s[si];
        mbuf[row * 3 + 1] = p_s[si];
        mbuf[row * 3 + 2] = n_s[si];
      }
  }
  __syncthreads();
  if (wj == 0 && l15 == 0) {
    #pragma unroll
    for (int ti = 0; ti < 4; ++ti)
      #pragma unroll
      for (int r = 0; r < 4; ++r) {
        int row = wi + ti * 16 + quad * 4 + r;
        int si = ti * 4 + r;
        float m = m_s[si], p = p_s[si], n = n_s[si];
        float om = mbuf[row * 3 + 0], op = mbuf[row * 3 + 1], on = mbuf[row * 3 + 2];
        float nm = fmaxf(m, om);
        float s0 = __expf(m - nm), s1 = __expf(om - nm);
        p = p * s0 + op * s1;
        n = n * s0 + on * s1;
        part[(size_t)blockIdx.y * B_ROWS + rowBase + row] = make_float4(nm, p, n, 0.f);
      }
  }
}

__global__ void merge_kernel(const float4* __restrict__ part,
                             const int* __restrict__ rsv,
                             float* __restrict__ accum) {
  int row = blockIdx.x * blockDim.x + threadIdx.x;
  float M = -INFINITY;
  #pragma unroll
  for (int c = 0; c < NCHUNK; ++c)
    M = fmaxf(M, part[(size_t)c * B_ROWS + row].x);
  float p = 0.f, n = 0.f;
  #pragma unroll
  for (int c = 0; c < NCHUNK; ++c) {
    float4 v = part[(size_t)c * B_ROWS + row];
    float s = __expf(v.x - M);
    p += v.y * s;
    n += v.z * s;
  }
  bool has = rsv[row] > 0;  // exact: has_pos <=> row_sum > 0
  float per = has ? -logf(p / (p + n)) : 0.f;
  float cnt = has ? 1.f : 0.f;
  #pragma unroll
  for (int off = 32; off >= 1; off >>= 1) {
    per += __shfl_xor(per, off);
    cnt += __shfl_xor(cnt, off);
  }
  if ((threadIdx.x & 63) == 0) {
    atomicAdd(accum + 0, per);
    atomicAdd(accum + 1, cnt);
  }
}

__global__ void fin_kernel(const float* __restrict__ accum, float* __restrict__ out) {
  out[0] = accum[0] / fmaxf(accum[1], 1.0f);
}

extern "C" void kernel_launch(void* const* d_in, const int* in_sizes, int n_in,
                              void* d_out, int out_size, void* d_ws, size_t ws_size,
                              hipStream_t stream) {
  const float* feat = (const float*)d_in[0];
  const float* labels = (const float*)d_in[1];
  float* out = (float*)d_out;
  char* ws = (char*)d_ws;
  // workspace layout (needs ~4.3 MB):
  float* accum = (float*)(ws + 0);                              // 16 B
  int* rsv = (int*)(ws + 16);                                   // 16 KB
  uint4* Lbm = (uint4*)(ws + 16 + 16384);                       // 64 KB
  unsigned short* cfA = (unsigned short*)(ws + 81952);          // 1 MB
  unsigned short* cfB = (unsigned short*)(ws + 81952 + 1048576);// 2 MB
  float4* part = (float4*)(ws + 81952 + 1048576 + 2097152);     // 1 MB

  hipLaunchKernelGGL(zero_kernel, dim3(1), dim3(64), 0, stream, accum);
  hipLaunchKernelGGL(pack_kernel, dim3(VB / 4), dim3(256), 0, stream,
                     feat, labels, cfA, cfB, Lbm, rsv);
  hipLaunchKernelGGL(main_kernel, dim3(32, NCHUNK), dim3(256), 0, stream,
                     cfA, cfB, Lbm, rsv, part);
  hipLaunchKernelGGL(merge_kernel, dim3(B_ROWS / 256), dim3(256), 0, stream,
                     part, rsv, accum);
  hipLaunchKernelGGL(fin_kernel, dim3(1), dim3(1), 0, stream, accum, out);
}

// Round 3
// 85.050 us; speedup vs baseline: 1.1493x; 1.1493x over previous
//
#include <hip/hip_runtime.h>
#include <math.h>

#define B_ROWS 4096
#define NVIEW 2
#define DIM 128
#define LBL 100
#define VB 8192
#define NCHUNK 16
#define CHUNK 512

typedef __attribute__((ext_vector_type(8))) short bf16x8;
typedef __attribute__((ext_vector_type(4))) float f32x4;

__device__ __forceinline__ unsigned short f2bf(float x) {
  union { float f; unsigned u; } a; a.f = x;
  unsigned r = a.u + 0x7fffu + ((a.u >> 16) & 1u);  // RNE
  return (unsigned short)(r >> 16);
}

// One wave per contrast-feature row j (j<B: view0, else view1).
// Produces: cfA = bf16(f/T) rows [0,B); cfB = bf16(f) rows [0,VB);
//           Lb = 128-bit label masks; rsv = label row sums;
//           seedv = lower bound on the bf16 diagonal dot (row max seed).
// Block 0 also zeroes the accumulator (zero_kernel folded in).
__global__ void pack_kernel(const float* __restrict__ feat,
                            const float* __restrict__ labels,
                            unsigned short* __restrict__ cfA,
                            unsigned short* __restrict__ cfB,
                            uint4* __restrict__ Lb,
                            int* __restrict__ rsv,
                            float* __restrict__ seedv,
                            float* __restrict__ accum) {
  const float invT = 1.0f / 0.07f;
  if (blockIdx.x == 0 && threadIdx.x < 2) accum[threadIdx.x] = 0.0f;
  int w = (int)((blockIdx.x * blockDim.x + threadIdx.x) >> 6);
  int lane = threadIdx.x & 63;
  if (w >= VB) return;
  int b = w & (B_ROWS - 1);
  int v = w >> 12;
  const float2* src = (const float2*)(feat + ((size_t)b * NVIEW + v) * DIM);
  float2 f = src[lane];
  unsigned ub0 = f2bf(f.x), ub1 = f2bf(f.y);
  ((unsigned*)(cfB + (size_t)w * DIM))[lane] = ub0 | (ub1 << 16);
  if (v == 0) {  // wave-uniform
    unsigned ua0 = f2bf(f.x * invT), ua1 = f2bf(f.y * invT);
    ((unsigned*)(cfA + (size_t)w * DIM))[lane] = ua0 | (ua1 << 16);
    // diagonal dot of the bf16-converted values, fp32 accumulate
    float s = __uint_as_float(ua0 << 16) * __uint_as_float(ub0 << 16) +
              __uint_as_float(ua1 << 16) * __uint_as_float(ub1 << 16);
    #pragma unroll
    for (int off = 32; off >= 1; off >>= 1) s += __shfl_xor(s, off);
    float x0 = labels[(size_t)w * LBL + lane];
    float x1 = (lane < LBL - 64) ? labels[(size_t)w * LBL + 64 + lane] : 0.0f;
    unsigned long long b0 = __ballot(x0 != 0.0f);
    unsigned long long b1 = __ballot(x1 != 0.0f);
    if (lane == 0) {
      Lb[w] = make_uint4((unsigned)b0, (unsigned)(b0 >> 32),
                         (unsigned)b1, (unsigned)(b1 >> 32));
      rsv[w] = __popcll(b0) + __popcll(b1);
      seedv[w] = s - 2.0f;  // slack ≫ MFMA reassociation error, ≪ 90
    }
  }
}

// Main fused kernel: 128-row x 512-col block; MFMA dots + online softmax.
// m is SEEDED with a lower bound on the row's diagonal logit, so the
// masked-exp slow path fires only in the 32 diagonal tiles (everything it
// skips underflows to 0 after full-row-max subtraction in the reference too).
// LDS tiles stored as 16B chunks: chunk(r,kc)=kc*128+(r^kc) (XOR swizzle ->
// conflict-free frag reads AND staged writes).
__launch_bounds__(256, 2)
__global__ void main_kernel(const unsigned short* __restrict__ cfA,
                            const unsigned short* __restrict__ cfB,
                            const uint4* __restrict__ Lb,
                            const int* __restrict__ rsv,
                            const float* __restrict__ seedv,
                            float4* __restrict__ part) {
  __shared__ uint4 As[2048];  // 32 KB: 128 rows x K=128 bf16
  __shared__ uint4 Bs[2048];  // 32 KB
  const int tid = threadIdx.x;
  const int lane = tid & 63;
  const int wave = tid >> 6;
  const int l15 = lane & 15;
  const int quad = lane >> 4;
  const int wi = (wave & 1) * 64;   // wave row offset in 128
  const int wj = (wave >> 1) * 64;  // wave col offset in 128
  const int rowBase = blockIdx.x * 128;
  const int chunkBase = blockIdx.y * CHUNK;
  const bool maskRegion = (chunkBase < B_ROWS);

  {  // stage A once (rows fixed for whole block)
    const uint4* srcA = (const uint4*)(cfA + (size_t)rowBase * DIM);
    #pragma unroll
    for (int it = 0; it < 8; ++it) {
      int flat = it * 256 + tid;
      int r = flat >> 4, kc = flat & 15;
      As[kc * 128 + (r ^ kc)] = srcA[flat];
    }
  }

  // online-softmax state: 16 rows per lane (fixed quad): row=wi+ti*16+quad*4+r
  // m seeded with (diag dot - 2): any logit below seed-87 underflows in the
  // reference as well, so skipping it is exact.
  float m_s[16], p_s[16], n_s[16];
  #pragma unroll
  for (int ti = 0; ti < 4; ++ti)
    #pragma unroll
    for (int r = 0; r < 4; ++r) {
      m_s[ti * 4 + r] = seedv[rowBase + wi + ti * 16 + quad * 4 + r];
      p_s[ti * 4 + r] = 0.f;
      n_s[ti * 4 + r] = 0.f;
    }

  const bf16x8* Asv = (const bf16x8*)As;
  const bf16x8* Bsv = (const bf16x8*)Bs;

  for (int jt = 0; jt < 4; ++jt) {
    const int colBase = chunkBase + jt * 128;
    __syncthreads();
    {
      const uint4* srcB = (const uint4*)(cfB + (size_t)colBase * DIM);
      #pragma unroll
      for (int it = 0; it < 8; ++it) {
        int flat = it * 256 + tid;
        int r = flat >> 4, kc = flat & 15;
        Bs[kc * 128 + (r ^ kc)] = srcB[flat];
      }
    }
    __syncthreads();

    // prefetch this tile's column label masks (coalesced; latency hidden
    // under the MFMA loop; only consumed by the rare slow path)
    uint4 clb[4];
    int crs[4];
    if (maskRegion) {
      #pragma unroll
      for (int tj = 0; tj < 4; ++tj) {
        int gcol = colBase + wj + tj * 16 + l15;
        clb[tj] = Lb[gcol];
        crs[tj] = rsv[gcol];
      }
    }

    f32x4 acc[4][4];
    #pragma unroll
    for (int ti = 0; ti < 4; ++ti)
      #pragma unroll
      for (int tj = 0; tj < 4; ++tj)
        acc[ti][tj] = (f32x4){0.f, 0.f, 0.f, 0.f};

    #pragma unroll
    for (int ks = 0; ks < 4; ++ks) {
      const int kc = ks * 4 + quad;
      const int abase = kc * 128 + wi + (l15 ^ kc);
      const int bbase = kc * 128 + wj + (l15 ^ kc);
      bf16x8 af[4], bfr[4];
      #pragma unroll
      for (int t = 0; t < 4; ++t) {
        af[t] = Asv[abase + t * 16];
        bfr[t] = Bsv[bbase + t * 16];
      }
      #pragma unroll
      for (int ti = 0; ti < 4; ++ti)
        #pragma unroll
        for (int tj = 0; tj < 4; ++tj)
          acc[ti][tj] = __builtin_amdgcn_mfma_f32_16x16x32_bf16(
              af[ti], bfr[tj], acc[ti][tj], 0, 0, 0);
    }

    // epilogue: C[row][col], row=wi+ti*16+quad*4+r, col=wj+tj*16+l15 (+bases)
    if (!maskRegion) {
      #pragma unroll
      for (int ti = 0; ti < 4; ++ti)
        #pragma unroll
        for (int r = 0; r < 4; ++r) {
          float tm = fmaxf(fmaxf(acc[ti][0][r], acc[ti][1][r]),
                           fmaxf(acc[ti][2][r], acc[ti][3][r]));
          int si = ti * 4 + r;
          m_s[si] = fmaxf(m_s[si], tm);
        }
    } else {
      #pragma unroll
      for (int ti = 0; ti < 4; ++ti)
        #pragma unroll
        for (int r = 0; r < 4; ++r) {
          int si = ti * 4 + r;
          float l0 = acc[ti][0][r], l1 = acc[ti][1][r];
          float l2 = acc[ti][2][r], l3 = acc[ti][3][r];
          float tm = fmaxf(fmaxf(l0, l1), fmaxf(l2, l3));
          float m = m_s[si];
          if (tm > m - 90.0f) {  // slow path: something survives exp
            int grow = rowBase + wi + ti * 16 + quad * 4 + r;
            uint4 la = Lb[grow];
            int ra = rsv[grow];
            float newm = fmaxf(m, tm);
            float sc = __expf(m - newm);
            float p = p_s[si] * sc, n = n_s[si] * sc;
            float lv[4] = {l0, l1, l2, l3};
            #pragma unroll
            for (int tj = 0; tj < 4; ++tj) {
              float e = __expf(lv[tj] - newm);
              int inter = __popc(la.x & clb[tj].x) + __popc(la.y & clb[tj].y) +
                          __popc(la.z & clb[tj].z) + __popc(la.w & clb[tj].w);
              if (3 * inter > ra + crs[tj]) p += e; else n += e;  // sim>=0.5 exact
            }
            m_s[si] = newm; p_s[si] = p; n_s[si] = n;
          }
        }
    }
  }

  // reduce across the 16 lanes (same quad) that share each row
  #pragma unroll
  for (int si = 0; si < 16; ++si) {
    float m = m_s[si], p = p_s[si], n = n_s[si];
    #pragma unroll
    for (int off = 8; off >= 1; off >>= 1) {
      float om = __shfl_xor(m, off);
      float op = __shfl_xor(p, off);
      float on = __shfl_xor(n, off);
      float nm = fmaxf(m, om);
      float s0 = __expf(m - nm), s1 = __expf(om - nm);
      p = p * s0 + op * s1;
      n = n * s0 + on * s1;
      m = nm;
    }
    m_s[si] = m; p_s[si] = p; n_s[si] = n;
  }

  // merge the two waves sharing each row (wj=0 and wj=64) via LDS, then store
  __syncthreads();
  float* mbuf = (float*)As;
  if (wj == 64 && l15 == 0) {
    #pragma unroll
    for (int ti = 0; ti < 4; ++ti)
      #pragma unroll
      for (int r = 0; r < 4; ++r) {
        int row = wi + ti * 16 + quad * 4 + r;
        int si = ti * 4 + r;
        mbuf[row * 3 + 0] = m_s[si];
        mbuf[row * 3 + 1] = p_s[si];
        mbuf[row * 3 + 2] = n_s[si];
      }
  }
  __syncthreads();
  if (wj == 0 && l15 == 0) {
    #pragma unroll
    for (int ti = 0; ti < 4; ++ti)
      #pragma unroll
      for (int r = 0; r < 4; ++r) {
        int row = wi + ti * 16 + quad * 4 + r;
        int si = ti * 4 + r;
        float m = m_s[si], p = p_s[si], n = n_s[si];
        float om = mbuf[row * 3 + 0], op = mbuf[row * 3 + 1], on = mbuf[row * 3 + 2];
        float nm = fmaxf(m, om);
        float s0 = __expf(m - nm), s1 = __expf(om - nm);
        p = p * s0 + op * s1;
        n = n * s0 + on * s1;
        part[(size_t)blockIdx.y * B_ROWS + rowBase + row] = make_float4(nm, p, n, 0.f);
      }
  }
}

__global__ void merge_kernel(const float4* __restrict__ part,
                             const int* __restrict__ rsv,
                             float* __restrict__ accum) {
  int row = blockIdx.x * blockDim.x + threadIdx.x;
  float M = -INFINITY;
  #pragma unroll
  for (int c = 0; c < NCHUNK; ++c)
    M = fmaxf(M, part[(size_t)c * B_ROWS + row].x);
  float p = 0.f, n = 0.f;
  #pragma unroll
  for (int c = 0; c < NCHUNK; ++c) {
    float4 v = part[(size_t)c * B_ROWS + row];
    float s = __expf(v.x - M);
    p += v.y * s;
    n += v.z * s;
  }
  bool has = rsv[row] > 0;  // exact: has_pos <=> row_sum > 0
  float per = has ? -logf(p / (p + n)) : 0.f;
  float cnt = has ? 1.f : 0.f;
  #pragma unroll
  for (int off = 32; off >= 1; off >>= 1) {
    per += __shfl_xor(per, off);
    cnt += __shfl_xor(cnt, off);
  }
  if ((threadIdx.x & 63) == 0) {
    atomicAdd(accum + 0, per);
    atomicAdd(accum + 1, cnt);
  }
}

__global__ void fin_kernel(const float* __restrict__ accum, float* __restrict__ out) {
  out[0] = accum[0] / fmaxf(accum[1], 1.0f);
}

extern "C" void kernel_launch(void* const* d_in, const int* in_sizes, int n_in,
                              void* d_out, int out_size, void* d_ws, size_t ws_size,
                              hipStream_t stream) {
  const float* feat = (const float*)d_in[0];
  const float* labels = (const float*)d_in[1];
  float* out = (float*)d_out;
  char* ws = (char*)d_ws;
  // workspace layout (needs ~4.3 MB):
  float* accum = (float*)(ws + 0);                              // 16 B
  int* rsv = (int*)(ws + 16);                                   // 16 KB
  uint4* Lbm = (uint4*)(ws + 16 + 16384);                       // 64 KB
  unsigned short* cfA = (unsigned short*)(ws + 81952);          // 1 MB
  unsigned short* cfB = (unsigned short*)(ws + 81952 + 1048576);// 2 MB
  float4* part = (float4*)(ws + 81952 + 1048576 + 2097152);     // 1 MB
  float* seedv = (float*)(ws + 81952 + 1048576 + 2097152 + 1048576); // 16 KB

  hipLaunchKernelGGL(pack_kernel, dim3(VB / 4), dim3(256), 0, stream,
                     feat, labels, cfA, cfB, Lbm, rsv, seedv, accum);
  hipLaunchKernelGGL(main_kernel, dim3(32, NCHUNK), dim3(256), 0, stream,
                     cfA, cfB, Lbm, rsv, seedv, part);
  hipLaunchKernelGGL(merge_kernel, dim3(B_ROWS / 256), dim3(256), 0, stream,
                     part, rsv, accum);
  hipLaunchKernelGGL(fin_kernel, dim3(1), dim3(1), 0, stream, accum, out);
}